// Round 10
// baseline (124.630 us; speedup 1.0000x reference)
//
#include <hip/hip_runtime.h>
#include <hip/hip_fp8.h>

#define S_LEN 2048
#define D_MODEL 1024
#define NB 4

typedef unsigned short u16;
typedef __attribute__((ext_vector_type(8))) short short8;
typedef __attribute__((ext_vector_type(4))) float f32x4;
typedef __attribute__((ext_vector_type(16))) float f32x16;
typedef __attribute__((ext_vector_type(4))) unsigned short u16x4;
typedef __attribute__((ext_vector_type(4))) int i32x4;
typedef __attribute__((ext_vector_type(8))) int i32x8;

__device__ inline u16 f2bf(float f) {
  union { float f; unsigned u; } v; v.f = f;
  unsigned u = v.u;
  unsigned r = (u + 0x7FFFu + ((u >> 16) & 1u)) >> 16;
  return (u16)r;
}

__device__ inline float bf2f(u16 b) {
  union { unsigned u; float f; } v; v.u = ((unsigned)b) << 16;
  return v.f;
}

__device__ inline unsigned char f2e4m3(float f) {
  __hip_fp8_e4m3 q(f);
  return (unsigned char)q.__x;
}

// fp4 e2m1 encode (round to nearest level in {0,.5,1,1.5,2,3,4,6})
__device__ inline unsigned f2e2m1(float f) {
  const unsigned s = (f < 0.0f) ? 8u : 0u;
  const float e = fabsf(f);
  unsigned c;
  c = (e < 0.25f) ? 0u : (e < 0.75f) ? 1u : (e < 1.25f) ? 2u : (e < 1.75f) ? 3u
      : (e < 2.5f) ? 4u : (e < 3.5f) ? 5u : (e < 5.0f) ? 6u : 7u;
  return s | c;
}

__device__ inline void glds16(const void* g, void* l) {
  __builtin_amdgcn_global_load_lds((const __attribute__((address_space(1))) void*)g,
                                   (__attribute__((address_space(3))) void*)l,
                                   16, 0, 0);
}

__device__ inline i32x8 cat8(i32x4 a, i32x4 b) {
  i32x8 r;
  r[0] = a[0]; r[1] = a[1]; r[2] = a[2]; r[3] = a[3];
  r[4] = b[0]; r[5] = b[1]; r[6] = b[2]; r[7] = b[3];
  return r;
}

__device__ inline i32x8 lo4(i32x4 a) {
  i32x8 r;
  r[0] = a[0]; r[1] = a[1]; r[2] = a[2]; r[3] = a[3];
  r[4] = 0; r[5] = 0; r[6] = 0; r[7] = 0;
  return r;
}

// ---------------- w2[t] = sum_n Wk[t][n] * bq[n]  (one wave per row) ----------------
__global__ __launch_bounds__(256) void w2_kernel(const float* __restrict__ Wk,
                                                 const float* __restrict__ bq,
                                                 float* __restrict__ w2) {
  const int r = blockIdx.x * 4 + (threadIdx.x >> 6);
  const int lane = threadIdx.x & 63;
  const f32x4* row = (const f32x4*)(Wk + (size_t)r * D_MODEL);
  float s = 0.0f;
  #pragma unroll
  for (int c = 0; c < 4; ++c) {
    const f32x4 v = row[lane * 4 + c];
    const f32x4 b = ((const f32x4*)bq)[lane * 4 + c];
    s += v[0]*b[0] + v[1]*b[1] + v[2]*b[2] + v[3]*b[3];
  }
  for (int o = 32; o > 0; o >>= 1) s += __shfl_xor(s, o);
  if (lane == 0) w2[r] = s;
}

// ---------------- LayerNorm: fp32 in -> fp8 X8 + fp4 X4 (2x pre-scale) + fused bvec ----------------
__global__ __launch_bounds__(256) void ln_kernel(const float* __restrict__ ctx,
                                                 const float* __restrict__ gamma,
                                                 const float* __restrict__ beta,
                                                 const float* __restrict__ w2,
                                                 unsigned char* __restrict__ x8,
                                                 unsigned char* __restrict__ x4,
                                                 float* __restrict__ bvec) {
  const int row = blockIdx.x;
  const int t = threadIdx.x;
  const f32x4 v = ((const f32x4*)(ctx + (size_t)row * D_MODEL))[t];
  float s = v[0] + v[1] + v[2] + v[3];
  float q = v[0]*v[0] + v[1]*v[1] + v[2]*v[2] + v[3]*v[3];
  for (int o = 32; o > 0; o >>= 1) { s += __shfl_xor(s, o); q += __shfl_xor(q, o); }
  __shared__ float rs[4], rq[4], rd[4];
  const int wave = t >> 6, lane = t & 63;
  if (lane == 0) { rs[wave] = s; rq[wave] = q; }
  __syncthreads();
  s = rs[0] + rs[1] + rs[2] + rs[3];
  q = rq[0] + rq[1] + rq[2] + rq[3];
  const float mu = s * (1.0f / D_MODEL);
  const float var = q * (1.0f / D_MODEL) - mu * mu;
  const float rstd = rsqrtf(var + 1e-3f);
  const f32x4 g4 = ((const f32x4*)gamma)[t];
  const f32x4 b4 = ((const f32x4*)beta)[t];
  const f32x4 w4 = ((const f32x4*)w2)[t];
  float xv[4];
  float dot = 0.0f;
  #pragma unroll
  for (int u = 0; u < 4; ++u) {
    xv[u] = (v[u] - mu) * rstd * g4[u] + b4[u];
    dot += xv[u] * w4[u];
  }
  unsigned pk = (unsigned)f2e4m3(xv[0]) | ((unsigned)f2e4m3(xv[1]) << 8) |
                ((unsigned)f2e4m3(xv[2]) << 16) | ((unsigned)f2e4m3(xv[3]) << 24);
  ((unsigned*)(x8 + (size_t)row * D_MODEL))[t] = pk;
  // fp4: thread owns k = 4t..4t+3 -> 4 nibbles -> u16
  unsigned n0 = f2e2m1(2.0f * xv[0]), n1 = f2e2m1(2.0f * xv[1]);
  unsigned n2 = f2e2m1(2.0f * xv[2]), n3 = f2e2m1(2.0f * xv[3]);
  ((u16*)(x4 + (size_t)row * (D_MODEL / 2)))[t] = (u16)(n0 | (n1 << 4) | (n2 << 8) | (n3 << 12));
  for (int of = 32; of > 0; of >>= 1) dot += __shfl_xor(dot, of);
  if (lane == 0) rd[wave] = dot;
  __syncthreads();
  if (t == 0) bvec[row] = (rd[0] + rd[1] + rd[2] + rd[3]) * (1.0f / D_MODEL);
}

// ---------------- weight prep: Wt[n][k] = bf16(W[k][n]); rows [0,1024)=Wq^T, [1024,2048)=Wk^T ----------------
__global__ __launch_bounds__(256) void prep_w(const float* __restrict__ Wq,
                                              const float* __restrict__ Wk,
                                              u16* __restrict__ Wt) {
  __shared__ float tile[32][33];
  const int k0 = blockIdx.x * 32;
  const int n0 = blockIdx.y * 32;
  const int tx = threadIdx.x, ty = threadIdx.y;
  const float* W = (n0 < D_MODEL) ? Wq : Wk;
  const int nl0 = (n0 < D_MODEL) ? n0 : (n0 - D_MODEL);
  #pragma unroll
  for (int j = 0; j < 32; j += 8)
    tile[ty + j][tx] = W[(size_t)(k0 + ty + j) * D_MODEL + nl0 + tx];
  __syncthreads();
  #pragma unroll
  for (int j = 0; j < 32; j += 8)
    Wt[(size_t)(n0 + ty + j) * D_MODEL + k0 + tx] = f2bf(tile[tx][ty + j]);
}

// ---------------- bf16 GEMM: m97-style 128x128 tile (PT only), fp8 x16 output ----------------
__global__ __launch_bounds__(256, 2) void gemm_bt(
    const u16* __restrict__ A, int lda,
    const u16* __restrict__ Bt, int ldb,
    unsigned char* __restrict__ C8, int ldc,
    float scale, int K) {
  __shared__ u16 As[128][32];
  __shared__ u16 Bs[128][32];
  const int tid = threadIdx.x;
  const int wave = tid >> 6, lane = tid & 63;
  const size_t m0 = (size_t)blockIdx.y * 128;
  const size_t n0 = (size_t)blockIdx.x * 128;
  const int wr = (wave >> 1) * 64;
  const int wc = (wave & 1) * 64;
  const int strow = wave * 16 + (lane >> 2);
  const int stslot = (lane & 3) * 8;
  const int fr = lane & 15, fq = lane >> 4;

  f32x4 acc[4][4];
  #pragma unroll
  for (int i = 0; i < 4; ++i)
    #pragma unroll
    for (int j = 0; j < 4; ++j) acc[i][j] = (f32x4)(0.0f);

  for (int k0 = 0; k0 < K; k0 += 32) {
    const u16* ga = A + (m0 + strow) * lda + k0 + stslot;
    const u16* gb = Bt + (n0 + strow) * ldb + k0 + stslot;
    glds16(ga, &As[wave * 16][0]);
    glds16(ga + (size_t)64 * lda, &As[64 + wave * 16][0]);
    glds16(gb, &Bs[wave * 16][0]);
    glds16(gb + (size_t)64 * ldb, &Bs[64 + wave * 16][0]);
    __syncthreads();
    short8 af[4], bfv[4];
    #pragma unroll
    for (int mi = 0; mi < 4; ++mi) af[mi] = *(const short8*)&As[wr + mi * 16 + fr][fq * 8];
    #pragma unroll
    for (int ni = 0; ni < 4; ++ni) bfv[ni] = *(const short8*)&Bs[wc + ni * 16 + fr][fq * 8];
    #pragma unroll
    for (int mi = 0; mi < 4; ++mi)
      #pragma unroll
      for (int ni = 0; ni < 4; ++ni)
        acc[mi][ni] = __builtin_amdgcn_mfma_f32_16x16x32_bf16(af[mi], bfv[ni], acc[mi][ni], 0, 0, 0);
    __syncthreads();
  }

  #pragma unroll
  for (int mi = 0; mi < 4; ++mi)
    #pragma unroll
    for (int ni = 0; ni < 4; ++ni) {
      const size_t row = m0 + wr + mi * 16 + fq * 4;
      const size_t col = n0 + wc + ni * 16 + fr;
      #pragma unroll
      for (int r = 0; r < 4; ++r)
        C8[(row + r) * ldc + col] = f2e4m3(acc[mi][ni][r] * scale);
    }
}

// ---------------- 128x256 fp8 GEMM (y): mfma_scale 32x32x64, BK=128, fp4 output (2x pre-scale) ----------------
__global__ __launch_bounds__(512, 2) void gemm8pF8y(
    const unsigned char* __restrict__ A8,
    const unsigned char* __restrict__ B8,
    unsigned char* __restrict__ C4, int ldc4,   // fp4 out, ldc4 = bytes per row
    float scale, int K) {
  __shared__ char smem[98304];
  const int tid = threadIdx.x;
  const int wave = tid >> 6, lane = tid & 63;
  const int wm = wave >> 2, wn = wave & 3;
  const size_t m0 = (size_t)blockIdx.y * 128;
  const size_t n0 = (size_t)blockIdx.x * 256;
  const unsigned char* Ab = A8 + m0 * K;
  const unsigned char* Bb = B8 + n0 * K;
  const int perL = (lane >> 3) * K + (((lane & 7) ^ (lane >> 3)) * 16);
  const int r7l = lane & 7;
  const int hi = lane >> 5;
  const int l31 = lane & 31;
  const int swk0_0 = ((hi * 2) ^ r7l) * 16;
  const int swk0_1 = ((hi * 2 + 1) ^ r7l) * 16;
  const int swk1_0 = ((4 + hi * 2) ^ r7l) * 16;
  const int swk1_1 = ((4 + hi * 2 + 1) ^ r7l) * 16;
  const int aOff = wm * 8192 + l31 * 128;
  const int bOff = 16384 + wn * 8192 + l31 * 128;

  f32x16 acc[2][2];
  #pragma unroll
  for (int i = 0; i < 2; ++i)
    #pragma unroll
    for (int j = 0; j < 2; ++j) acc[i][j] = (f32x16)(0.0f);

#define YSTG_A(BUF, KK) do { \
    glds16(Ab + (size_t)(wave * 16) * K + perL + (KK), smem + (BUF) + wave * 2048); \
    glds16(Ab + (size_t)(wave * 16 + 8) * K + perL + (KK), smem + (BUF) + wave * 2048 + 1024); } while (0)
#define YSTG_BEV(BUF, KK) do { \
    glds16(Bb + (size_t)(wave * 32) * K + perL + (KK), smem + (BUF) + 16384 + wave * 4096); \
    glds16(Bb + (size_t)(wave * 32 + 8) * K + perL + (KK), smem + (BUF) + 16384 + wave * 4096 + 1024); } while (0)
#define YSTG_BOD(BUF, KK) do { \
    glds16(Bb + (size_t)(wave * 32 + 16) * K + perL + (KK), smem + (BUF) + 16384 + wave * 4096 + 2048); \
    glds16(Bb + (size_t)(wave * 32 + 24) * K + perL + (KK), smem + (BUF) + 16384 + wave * 4096 + 3072); } while (0)

  const int NT = K >> 7;
  YSTG_A(0, 0); YSTG_BEV(0, 0); YSTG_BOD(0, 0);

  for (int t = 0; t < NT; ++t) {
    const int bo = (t & 1) * 49152;
    const int bn = bo ^ 49152;
    const int kk = (t + 1 < NT) ? (t + 1) * 128 : 0;
    i32x8 afr[2], bfr[2];

    // ---- phase 0: ks0 ----
    asm volatile("s_waitcnt vmcnt(0)" ::: "memory");
    asm volatile("s_barrier" ::: "memory");
    #pragma unroll
    for (int mt = 0; mt < 2; ++mt)
      afr[mt] = cat8(*(const i32x4*)(smem + bo + aOff + mt * 4096 + swk0_0),
                     *(const i32x4*)(smem + bo + aOff + mt * 4096 + swk0_1));
    #pragma unroll
    for (int nt = 0; nt < 2; ++nt)
      bfr[nt] = cat8(*(const i32x4*)(smem + bo + bOff + nt * 4096 + swk0_0),
                     *(const i32x4*)(smem + bo + bOff + nt * 4096 + swk0_1));
    YSTG_A(bn, kk);
    YSTG_BEV(bn, kk);
    __builtin_amdgcn_s_setprio(1);
    #pragma unroll
    for (int mt = 0; mt < 2; ++mt)
      #pragma unroll
      for (int nt = 0; nt < 2; ++nt)
        acc[mt][nt] = __builtin_amdgcn_mfma_scale_f32_32x32x64_f8f6f4(
            afr[mt], bfr[nt], acc[mt][nt], 0, 0, 0, 0x7F7F7F7F, 0, 0x7F7F7F7F);
    __builtin_amdgcn_s_setprio(0);

    // ---- phase 1: ks1 ----
    asm volatile("s_barrier" ::: "memory");
    #pragma unroll
    for (int mt = 0; mt < 2; ++mt)
      afr[mt] = cat8(*(const i32x4*)(smem + bo + aOff + mt * 4096 + swk1_0),
                     *(const i32x4*)(smem + bo + aOff + mt * 4096 + swk1_1));
    #pragma unroll
    for (int nt = 0; nt < 2; ++nt)
      bfr[nt] = cat8(*(const i32x4*)(smem + bo + bOff + nt * 4096 + swk1_0),
                     *(const i32x4*)(smem + bo + bOff + nt * 4096 + swk1_1));
    YSTG_BOD(bn, kk);
    __builtin_amdgcn_s_setprio(1);
    #pragma unroll
    for (int mt = 0; mt < 2; ++mt)
      #pragma unroll
      for (int nt = 0; nt < 2; ++nt)
        acc[mt][nt] = __builtin_amdgcn_mfma_scale_f32_32x32x64_f8f6f4(
            afr[mt], bfr[nt], acc[mt][nt], 0, 0, 0, 0x7F7F7F7F, 0, 0x7F7F7F7F);
    __builtin_amdgcn_s_setprio(0);
  }
#undef YSTG_A
#undef YSTG_BEV
#undef YSTG_BOD

  // C/D layout 32x32: col = lane&31, row = (r&3) + 8*(r>>2) + 4*(lane>>5)
  // fp4 out: adjacent cols in adjacent lanes -> shfl-pair nibbles, even lane stores byte
  #pragma unroll
  for (int mt = 0; mt < 2; ++mt)
    #pragma unroll
    for (int nt = 0; nt < 2; ++nt) {
      const size_t colg = n0 + wn * 64 + nt * 32 + l31;
      #pragma unroll
      for (int r = 0; r < 16; ++r) {
        const size_t rowg = m0 + wm * 64 + mt * 32 + (r & 3) + 8 * (r >> 2) + 4 * hi;
        const unsigned qn = f2e2m1(2.0f * acc[mt][nt][r] * scale);
        const unsigned qp = (unsigned)__shfl_xor((int)qn, 1);
        if (!(lane & 1))
          C4[rowg * ldc4 + (colg >> 1)] = (unsigned char)(qn | (qp << 4));
      }
    }
}

// ---------------- 256x256 fp4 GEMM (scores): mfma_scale 32x32x64 FMT=4, BK=256, 8 waves ----------------
// Same byte geometry as the validated fp8 kernel: 128B LDS rows, 2x64KB buffers, row-XOR 16B-slot swizzle.
// NT = K/256 tiles; 4 phases/tile (ks0..ks3), 8 MFMA each; staging 8 glds/wave split p0/p1; vmcnt(0) at p0.
__global__ __launch_bounds__(512, 2) void gemm8pF4(
    const unsigned char* __restrict__ A4, long long sA,   // byte strides
    const unsigned char* __restrict__ B4, long long sB,
    u16* __restrict__ C, int ldc, long long sC,
    float scale, int K) {                                  // K in elements
  __shared__ char smem[131072];
  const int tid = threadIdx.x;
  const int wave = tid >> 6, lane = tid & 63;
  const int wm = wave >> 2, wn = wave & 3;
  const int z = blockIdx.z;
  const int Kb = K >> 1;                                   // bytes per row (512)
  const size_t m0 = (size_t)blockIdx.y * 256;
  const size_t n0 = (size_t)blockIdx.x * 256;
  const unsigned char* Ab = A4 + (size_t)z * sA + m0 * Kb;
  const unsigned char* Bb = B4 + (size_t)z * sB + n0 * Kb;
  const int perL = (lane >> 3) * Kb + (((lane & 7) ^ (lane >> 3)) * 16);
  const int w4 = wave * 4;
  const int r7l = lane & 7;
  const int hi = lane >> 5;
  const int l31 = lane & 31;
  // fragment slot for ks-step: chunk = ks*2 + hi, swizzled
  const int aOff = wm * 16384 + l31 * 128;
  const int bOff = 32768 + wn * 8192 + l31 * 128;

  f32x16 acc[4][2];
  #pragma unroll
  for (int i = 0; i < 4; ++i)
    #pragma unroll
    for (int j = 0; j < 2; ++j) acc[i][j] = (f32x16)(0.0f);

#define STG_A4(BUF, KK, C0) do { \
    glds16(Ab + (size_t)((w4 + (C0)) * 8) * Kb + perL + (KK), smem + (BUF) + (w4 + (C0)) * 1024); \
    glds16(Ab + (size_t)((w4 + (C0) + 1) * 8) * Kb + perL + (KK), smem + (BUF) + (w4 + (C0) + 1) * 1024); } while (0)
#define STG_B4(BUF, KK, C0) do { \
    glds16(Bb + (size_t)((w4 + (C0)) * 8) * Kb + perL + (KK), smem + (BUF) + 32768 + (w4 + (C0)) * 1024); \
    glds16(Bb + (size_t)((w4 + (C0) + 1) * 8) * Kb + perL + (KK), smem + (BUF) + 32768 + (w4 + (C0) + 1) * 1024); } while (0)

  const int NT = K >> 8;  // BK=256 elements = 128 bytes
  STG_A4(0, 0, 0); STG_A4(0, 0, 2); STG_B4(0, 0, 0); STG_B4(0, 0, 2);

  for (int t = 0; t < NT; ++t) {
    const int bo = (t & 1) * 65536;
    const int bn = bo ^ 65536;
    const int kk = (t + 1 < NT) ? (t + 1) * 128 : 0;
    i32x8 afr[4], bfr[2];

    #pragma unroll
    for (int ks = 0; ks < 4; ++ks) {
      if (ks == 0) asm volatile("s_waitcnt vmcnt(0)" ::: "memory");
      asm volatile("s_barrier" ::: "memory");
      const int sw = ((ks * 2 + hi) ^ r7l) * 16;
      #pragma unroll
      for (int mt = 0; mt < 4; ++mt)
        afr[mt] = lo4(*(const i32x4*)(smem + bo + aOff + mt * 4096 + sw));
      #pragma unroll
      for (int nt = 0; nt < 2; ++nt)
        bfr[nt] = lo4(*(const i32x4*)(smem + bo + bOff + nt * 4096 + sw));
      if (ks == 0) { STG_A4(bn, kk, 0); STG_B4(bn, kk, 0); }
      if (ks == 1) { STG_A4(bn, kk, 2); STG_B4(bn, kk, 2); }
      __builtin_amdgcn_s_setprio(1);
      #pragma unroll
      for (int mt = 0; mt < 4; ++mt)
        #pragma unroll
        for (int nt = 0; nt < 2; ++nt)
          acc[mt][nt] = __builtin_amdgcn_mfma_scale_f32_32x32x64_f8f6f4(
              afr[mt], bfr[nt], acc[mt][nt], 4, 4, 0, 0x7F7F7F7F, 0, 0x7F7F7F7F);
      __builtin_amdgcn_s_setprio(0);
    }
  }
#undef STG_A4
#undef STG_B4

  u16* Cz = C + (size_t)z * sC;
  #pragma unroll
  for (int mt = 0; mt < 4; ++mt)
    #pragma unroll
    for (int nt = 0; nt < 2; ++nt) {
      const size_t colg = n0 + wn * 64 + nt * 32 + l31;
      #pragma unroll
      for (int r = 0; r < 16; ++r) {
        const size_t rowg = m0 + wm * 128 + mt * 32 + (r & 3) + 8 * (r >> 2) + 4 * hi;
        Cz[rowg * ldc + colg] = f2bf(acc[mt][nt][r] * scale);
      }
    }
}

// ---------------- row softmax + prior transform; emits na row, ell, dvec ----------------
__global__ __launch_bounds__(256) void softmax_kernel(const u16* __restrict__ Sb,
                                                      const float* __restrict__ bvec,
                                                      const float* __restrict__ prior,
                                                      float* __restrict__ na,
                                                      float* __restrict__ ell,
                                                      float* __restrict__ dvec) {
  const int row = blockIdx.x;
  const int t = threadIdx.x;
  const int b = row >> 11, i = row & (S_LEN - 1);
  const short8 sv = ((const short8*)(Sb + (size_t)row * S_LEN))[t];
  const f32x4 bv0 = ((const f32x4*)(bvec + (size_t)b * S_LEN))[t * 2];
  const f32x4 bv1 = ((const f32x4*)(bvec + (size_t)b * S_LEN))[t * 2 + 1];
  float v[8];
  #pragma unroll
  for (int u = 0; u < 8; ++u)
    v[u] = bf2f((u16)sv[u]) + ((u < 4) ? bv0[u] : bv1[u - 4]);
  float mx = v[0];
  #pragma unroll
  for (int u = 1; u < 8; ++u) mx = fmaxf(mx, v[u]);
  for (int o = 32; o > 0; o >>= 1) mx = fmaxf(mx, __shfl_xor(mx, o));
  __shared__ float red[4], red2[4];
  const int wave = t >> 6, lane = t & 63;
  if (lane == 0) red[wave] = mx;
  __syncthreads();
  mx = fmaxf(fmaxf(red[0], red[1]), fmaxf(red[2], red[3]));
  float e[8], s = 0.0f;
  #pragma unroll
  for (int u = 0; u < 8; ++u) { e[u] = __expf(v[u] - mx); s += e[u]; }
  for (int o = 32; o > 0; o >>= 1) s += __shfl_xor(s, o);
  if (lane == 0) red2[wave] = s;
  __syncthreads();
  s = red2[0] + red2[1] + red2[2] + red2[3];
  const float pr = prior[0];
  const float w = 1.0f - pr;
  const float inv = 1.0f / s;
  f32x4 o0, o1;
  #pragma unroll
  for (int u = 0; u < 4; ++u) o0[u] = pr + w * (e[u] * inv + 1e-9f);
  #pragma unroll
  for (int u = 0; u < 4; ++u) o1[u] = pr + w * (e[4 + u] * inv + 1e-9f);
  f32x4* nrow = (f32x4*)(na + (size_t)row * S_LEN);
  nrow[t * 2] = o0;
  nrow[t * 2 + 1] = o1;
  #pragma unroll
  for (int u = 0; u < 8; ++u) {
    const int j = t * 8 + u;
    const float ov = (u < 4) ? o0[u] : o1[u - 4];
    if (j == i) dvec[row] = ov;
    if (j == i + 1) ell[row] = logf(ov + 1e-9f);
  }
  if (i == S_LEN - 1 && t == 0) ell[row] = 0.0f;
}

// ---------------- exclusive prefix sum of ell -> Cpre ----------------
__global__ __launch_bounds__(256) void scan_kernel(const float* __restrict__ ell,
                                                   float* __restrict__ Cpre) {
  const int b = blockIdx.x, t = threadIdx.x;
  const float* eb = ell + (size_t)b * S_LEN;
  const f32x4 e0 = ((const f32x4*)eb)[t * 2];
  const f32x4 e1 = ((const f32x4*)eb)[t * 2 + 1];
  float ev[8];
  #pragma unroll
  for (int u = 0; u < 4; ++u) ev[u] = e0[u];
  #pragma unroll
  for (int u = 0; u < 4; ++u) ev[4 + u] = e1[u];
  float loc[8], tot = 0.0f;
  #pragma unroll
  for (int u = 0; u < 8; ++u) { loc[u] = tot; tot += ev[u]; }
  __shared__ float sbuf[256];
  sbuf[t] = tot;
  __syncthreads();
  for (int off = 1; off < 256; off <<= 1) {
    const float v = (t >= off) ? sbuf[t - off] : 0.0f;
    __syncthreads();
    sbuf[t] += v;
    __syncthreads();
  }
  const float base = (t == 0) ? 0.0f : sbuf[t - 1];
  #pragma unroll
  for (int u = 0; u < 8; ++u)
    Cpre[(size_t)b * S_LEN + t * 8 + u] = base + loc[u];
}

// ---------------- g_attn: exp(C[max]-C[min]) + 1e-9, diag from dvec ----------------
__global__ __launch_bounds__(256) void gattn_kernel(const float* __restrict__ Cpre,
                                                    const float* __restrict__ dvec,
                                                    float* __restrict__ g) {
  const int b = blockIdx.z, i = blockIdx.y;
  const int j0 = blockIdx.x * 1024 + threadIdx.x * 4;
  const float Ci = Cpre[b * S_LEN + i];
  const float di = dvec[b * S_LEN + i];
  const f32x4 Cj = *(const f32x4*)&Cpre[b * S_LEN + j0];
  f32x4 o;
  #pragma unroll
  for (int u = 0; u < 4; ++u) {
    const int j = j0 + u;
    const float arg = (j > i) ? (Cj[u] - Ci) : (Ci - Cj[u]);
    o[u] = (j == i) ? (di + 1e-9f) : (__expf(arg) + 1e-9f);
  }
  *(f32x4*)(g + ((size_t)b * S_LEN + i) * S_LEN + j0) = o;
}

extern "C" void kernel_launch(void* const* d_in, const int* in_sizes, int n_in,
                              void* d_out, int out_size, void* d_ws, size_t ws_size,
                              hipStream_t stream) {
  const float* ctx   = (const float*)d_in[0];
  // d_in[1] = eos_mask: numerically a no-op (mask * 1e-19 in fp32), never read.
  const float* prior = (const float*)d_in[2];
  const float* gamma = (const float*)d_in[3];
  const float* beta  = (const float*)d_in[4];
  const float* Wk    = (const float*)d_in[5];
  const float* Wq    = (const float*)d_in[7];
  const float* bq    = (const float*)d_in[8];

  float* g  = (float*)d_out;                               // g_attn output (also bf16 scores scratch)
  float* na = g + (size_t)NB * S_LEN * S_LEN;              // neibor_attn output

  // scratch inside the na output region (all dead before softmax overwrites it):
  unsigned char* X8 = (unsigned char*)na;                          // fp8 [8192][1024], 8 MiB
  unsigned char* X4 = X8 + (size_t)(NB * S_LEN) * D_MODEL;         // fp4 [8192][512B], 4 MiB
  unsigned char* Y4 = X4 + (size_t)(NB * S_LEN) * (D_MODEL / 2);   // fp4 [8192][512B], 4 MiB
  unsigned char* PT8 = Y4 + (size_t)(NB * S_LEN) * (D_MODEL / 2);  // fp8 [1024][1024], 1 MiB
  u16* Wt = (u16*)(PT8 + (size_t)D_MODEL * D_MODEL);               // [2048][1024] bf16, 4 MiB
  // bf16 scores live in the g output region (overwritten by gattn at the end):
  u16* Sb = (u16*)g;                                               // [8192][2048] bf16, 32 MiB
  // small scratch in ws:
  float* w2   = (float*)d_ws;                                      // [1024]
  float* bvec = w2 + D_MODEL;                                      // [8192]
  float* ell  = bvec + NB * S_LEN;                                 // [8192]
  float* dvec = ell + NB * S_LEN;                                  // [8192]
  float* Cpre = dvec + NB * S_LEN;                                 // [8192]

  w2_kernel<<<D_MODEL / 4, 256, 0, stream>>>(Wk, bq, w2);
  ln_kernel<<<NB * S_LEN, 256, 0, stream>>>(ctx, gamma, beta, w2, X8, X4, bvec);
  prep_w<<<dim3(32, 64), dim3(32, 8), 0, stream>>>(Wq, Wk, Wt);

  // PT8[n][k] = fp8(16 * P[k][n]), P = Wq·Wk^T
  gemm_bt<<<dim3(8, 8, 1), 256, 0, stream>>>(Wt + (size_t)D_MODEL * D_MODEL, D_MODEL,
                                             Wt, D_MODEL,
                                             PT8, D_MODEL, 16.0f, D_MODEL);
  // Y4 = fp4(2 * (x·P))  (fp8 MFMA; 1/16 undoes PT pre-scale, epilogue applies 2x fp4 pre-scale)
  gemm8pF8y<<<dim3(4, 64, 1), 512, 0, stream>>>(X8, PT8,
                                                Y4, D_MODEL / 2, 1.0f / 16.0f, D_MODEL);
  // scores[b] = (y4[b] · x4[b]^T) / d  (fp4 MFMA; operands carry 2x each -> /4)
  gemm8pF4<<<dim3(8, 8, NB), 512, 0, stream>>>(Y4, (long long)S_LEN * (D_MODEL / 2),
                                               X4, (long long)S_LEN * (D_MODEL / 2),
                                               Sb, S_LEN, (long long)S_LEN * S_LEN,
                                               1.0f / (4.0f * (float)D_MODEL), D_MODEL);

  softmax_kernel<<<NB * S_LEN, 256, 0, stream>>>(Sb, bvec, prior, na, ell, dvec);
  scan_kernel<<<NB, 256, 0, stream>>>(ell, Cpre);
  gattn_kernel<<<dim3(2, S_LEN, NB), 256, 0, stream>>>(Cpre, dvec, g);
}

// Round 11
// 116.805 us; speedup vs baseline: 1.0670x; 1.0670x over previous
//
#include <hip/hip_runtime.h>
#include <hip/hip_fp8.h>

#define S_LEN 2048
#define D_MODEL 1024
#define NB 4

typedef unsigned short u16;
typedef __attribute__((ext_vector_type(8))) short short8;
typedef __attribute__((ext_vector_type(4))) float f32x4;
typedef __attribute__((ext_vector_type(16))) float f32x16;
typedef __attribute__((ext_vector_type(4))) unsigned short u16x4;
typedef __attribute__((ext_vector_type(4))) int i32x4;
typedef __attribute__((ext_vector_type(8))) int i32x8;

__device__ inline u16 f2bf(float f) {
  union { float f; unsigned u; } v; v.f = f;
  unsigned u = v.u;
  unsigned r = (u + 0x7FFFu + ((u >> 16) & 1u)) >> 16;
  return (u16)r;
}

__device__ inline float bf2f(u16 b) {
  union { unsigned u; float f; } v; v.u = ((unsigned)b) << 16;
  return v.f;
}

__device__ inline unsigned char f2e4m3(float f) {
  __hip_fp8_e4m3 q(f);
  return (unsigned char)q.__x;
}

__device__ inline float e4m32f(unsigned char b) {
  __hip_fp8_e4m3 q;
  q.__x = b;
  return (float)q;
}

__device__ inline void glds16(const void* g, void* l) {
  __builtin_amdgcn_global_load_lds((const __attribute__((address_space(1))) void*)g,
                                   (__attribute__((address_space(3))) void*)l,
                                   16, 0, 0);
}

__device__ inline i32x8 cat8(i32x4 a, i32x4 b) {
  i32x8 r;
  r[0] = a[0]; r[1] = a[1]; r[2] = a[2]; r[3] = a[3];
  r[4] = b[0]; r[5] = b[1]; r[6] = b[2]; r[7] = b[3];
  return r;
}

// ---------------- weight prep (+ fused w2 = Wk·bq at blockIdx.y==64) ----------------
// Wt[n][k] = bf16(W[k][n]); rows [0,1024)=Wq^T, [1024,2048)=Wk^T
__global__ __launch_bounds__(256) void prep_w(const float* __restrict__ Wq,
                                              const float* __restrict__ Wk,
                                              const float* __restrict__ bq,
                                              u16* __restrict__ Wt,
                                              float* __restrict__ w2) {
  if (blockIdx.y == 64) {
    const int tid = threadIdx.y * 32 + threadIdx.x;
    const int wave = tid >> 6, lane = tid & 63;
    const int r0 = blockIdx.x * 32 + wave * 8;
    #pragma unroll
    for (int rr = 0; rr < 8; ++rr) {
      const int r = r0 + rr;
      const f32x4* row = (const f32x4*)(Wk + (size_t)r * D_MODEL);
      float s = 0.0f;
      #pragma unroll
      for (int c = 0; c < 4; ++c) {
        const f32x4 v = row[lane * 4 + c];
        const f32x4 b = ((const f32x4*)bq)[lane * 4 + c];
        s += v[0]*b[0] + v[1]*b[1] + v[2]*b[2] + v[3]*b[3];
      }
      for (int o = 32; o > 0; o >>= 1) s += __shfl_xor(s, o);
      if (lane == 0) w2[r] = s;
    }
    return;
  }
  __shared__ float tile[32][33];
  const int k0 = blockIdx.x * 32;
  const int n0 = blockIdx.y * 32;
  const int tx = threadIdx.x, ty = threadIdx.y;
  const float* W = (n0 < D_MODEL) ? Wq : Wk;
  const int nl0 = (n0 < D_MODEL) ? n0 : (n0 - D_MODEL);
  #pragma unroll
  for (int j = 0; j < 32; j += 8)
    tile[ty + j][tx] = W[(size_t)(k0 + ty + j) * D_MODEL + nl0 + tx];
  __syncthreads();
  #pragma unroll
  for (int j = 0; j < 32; j += 8)
    Wt[(size_t)(n0 + ty + j) * D_MODEL + k0 + tx] = f2bf(tile[tx][ty + j]);
}

// ---------------- LayerNorm: fp32 in -> fp8 X8 + fused bvec ----------------
__global__ __launch_bounds__(256) void ln_kernel(const float* __restrict__ ctx,
                                                 const float* __restrict__ gamma,
                                                 const float* __restrict__ beta,
                                                 const float* __restrict__ w2,
                                                 unsigned char* __restrict__ x8,
                                                 float* __restrict__ bvec) {
  const int row = blockIdx.x;
  const int t = threadIdx.x;
  const f32x4 v = ((const f32x4*)(ctx + (size_t)row * D_MODEL))[t];
  float s = v[0] + v[1] + v[2] + v[3];
  float q = v[0]*v[0] + v[1]*v[1] + v[2]*v[2] + v[3]*v[3];
  for (int o = 32; o > 0; o >>= 1) { s += __shfl_xor(s, o); q += __shfl_xor(q, o); }
  __shared__ float rs[4], rq[4], rd[4];
  const int wave = t >> 6, lane = t & 63;
  if (lane == 0) { rs[wave] = s; rq[wave] = q; }
  __syncthreads();
  s = rs[0] + rs[1] + rs[2] + rs[3];
  q = rq[0] + rq[1] + rq[2] + rq[3];
  const float mu = s * (1.0f / D_MODEL);
  const float var = q * (1.0f / D_MODEL) - mu * mu;
  const float rstd = rsqrtf(var + 1e-3f);
  const f32x4 g4 = ((const f32x4*)gamma)[t];
  const f32x4 b4 = ((const f32x4*)beta)[t];
  const f32x4 w4 = ((const f32x4*)w2)[t];
  float xv[4];
  float dot = 0.0f;
  #pragma unroll
  for (int u = 0; u < 4; ++u) {
    xv[u] = (v[u] - mu) * rstd * g4[u] + b4[u];
    dot += xv[u] * w4[u];
  }
  unsigned pk = (unsigned)f2e4m3(xv[0]) | ((unsigned)f2e4m3(xv[1]) << 8) |
                ((unsigned)f2e4m3(xv[2]) << 16) | ((unsigned)f2e4m3(xv[3]) << 24);
  ((unsigned*)(x8 + (size_t)row * D_MODEL))[t] = pk;
  for (int of = 32; of > 0; of >>= 1) dot += __shfl_xor(dot, of);
  if (lane == 0) rd[wave] = dot;
  __syncthreads();
  if (t == 0) bvec[row] = (rd[0] + rd[1] + rd[2] + rd[3]) * (1.0f / D_MODEL);
}

// ---------------- bf16 GEMM: m97-style 128x128 tile (PT only), fp8 x16 output ----------------
__global__ __launch_bounds__(256, 2) void gemm_bt(
    const u16* __restrict__ A, int lda,
    const u16* __restrict__ Bt, int ldb,
    unsigned char* __restrict__ C8, int ldc,
    float scale, int K) {
  __shared__ u16 As[128][32];
  __shared__ u16 Bs[128][32];
  const int tid = threadIdx.x;
  const int wave = tid >> 6, lane = tid & 63;
  const size_t m0 = (size_t)blockIdx.y * 128;
  const size_t n0 = (size_t)blockIdx.x * 128;
  const int wr = (wave >> 1) * 64;
  const int wc = (wave & 1) * 64;
  const int strow = wave * 16 + (lane >> 2);
  const int stslot = (lane & 3) * 8;
  const int fr = lane & 15, fq = lane >> 4;

  f32x4 acc[4][4];
  #pragma unroll
  for (int i = 0; i < 4; ++i)
    #pragma unroll
    for (int j = 0; j < 4; ++j) acc[i][j] = (f32x4)(0.0f);

  for (int k0 = 0; k0 < K; k0 += 32) {
    const u16* ga = A + (m0 + strow) * lda + k0 + stslot;
    const u16* gb = Bt + (n0 + strow) * ldb + k0 + stslot;
    glds16(ga, &As[wave * 16][0]);
    glds16(ga + (size_t)64 * lda, &As[64 + wave * 16][0]);
    glds16(gb, &Bs[wave * 16][0]);
    glds16(gb + (size_t)64 * ldb, &Bs[64 + wave * 16][0]);
    __syncthreads();
    short8 af[4], bfv[4];
    #pragma unroll
    for (int mi = 0; mi < 4; ++mi) af[mi] = *(const short8*)&As[wr + mi * 16 + fr][fq * 8];
    #pragma unroll
    for (int ni = 0; ni < 4; ++ni) bfv[ni] = *(const short8*)&Bs[wc + ni * 16 + fr][fq * 8];
    #pragma unroll
    for (int mi = 0; mi < 4; ++mi)
      #pragma unroll
      for (int ni = 0; ni < 4; ++ni)
        acc[mi][ni] = __builtin_amdgcn_mfma_f32_16x16x32_bf16(af[mi], bfv[ni], acc[mi][ni], 0, 0, 0);
    __syncthreads();
  }

  #pragma unroll
  for (int mi = 0; mi < 4; ++mi)
    #pragma unroll
    for (int ni = 0; ni < 4; ++ni) {
      const size_t row = m0 + wr + mi * 16 + fq * 4;
      const size_t col = n0 + wc + ni * 16 + fr;
      #pragma unroll
      for (int r = 0; r < 4; ++r)
        C8[(row + r) * ldc + col] = f2e4m3(acc[mi][ni][r] * scale);
    }
}

// ---------------- 128x256 fp8 GEMM (y): mfma_scale 32x32x64, BK=128, 8 waves, 2 phases/K-tile ----------------
__global__ __launch_bounds__(512, 2) void gemm8pF8y(
    const unsigned char* __restrict__ A8,
    const unsigned char* __restrict__ B8,
    unsigned char* __restrict__ C8, int ldc,
    float scale, int K) {
  __shared__ char smem[98304];
  const int tid = threadIdx.x;
  const int wave = tid >> 6, lane = tid & 63;
  const int wm = wave >> 2, wn = wave & 3;
  const size_t m0 = (size_t)blockIdx.y * 128;
  const size_t n0 = (size_t)blockIdx.x * 256;
  const unsigned char* Ab = A8 + m0 * K;
  const unsigned char* Bb = B8 + n0 * K;
  const int perL = (lane >> 3) * K + (((lane & 7) ^ (lane >> 3)) * 16);
  const int r7l = lane & 7;
  const int hi = lane >> 5;
  const int l31 = lane & 31;
  const int swk0_0 = ((hi * 2) ^ r7l) * 16;
  const int swk0_1 = ((hi * 2 + 1) ^ r7l) * 16;
  const int swk1_0 = ((4 + hi * 2) ^ r7l) * 16;
  const int swk1_1 = ((4 + hi * 2 + 1) ^ r7l) * 16;
  const int aOff = wm * 8192 + l31 * 128;
  const int bOff = 16384 + wn * 8192 + l31 * 128;

  f32x16 acc[2][2];
  #pragma unroll
  for (int i = 0; i < 2; ++i)
    #pragma unroll
    for (int j = 0; j < 2; ++j) acc[i][j] = (f32x16)(0.0f);

#define YSTG_A(BUF, KK) do { \
    glds16(Ab + (size_t)(wave * 16) * K + perL + (KK), smem + (BUF) + wave * 2048); \
    glds16(Ab + (size_t)(wave * 16 + 8) * K + perL + (KK), smem + (BUF) + wave * 2048 + 1024); } while (0)
#define YSTG_BEV(BUF, KK) do { \
    glds16(Bb + (size_t)(wave * 32) * K + perL + (KK), smem + (BUF) + 16384 + wave * 4096); \
    glds16(Bb + (size_t)(wave * 32 + 8) * K + perL + (KK), smem + (BUF) + 16384 + wave * 4096 + 1024); } while (0)
#define YSTG_BOD(BUF, KK) do { \
    glds16(Bb + (size_t)(wave * 32 + 16) * K + perL + (KK), smem + (BUF) + 16384 + wave * 4096 + 2048); \
    glds16(Bb + (size_t)(wave * 32 + 24) * K + perL + (KK), smem + (BUF) + 16384 + wave * 4096 + 3072); } while (0)

  const int NT = K >> 7;
  YSTG_A(0, 0); YSTG_BEV(0, 0); YSTG_BOD(0, 0);

  for (int t = 0; t < NT; ++t) {
    const int bo = (t & 1) * 49152;
    const int bn = bo ^ 49152;
    const int kk = (t + 1 < NT) ? (t + 1) * 128 : 0;
    i32x8 afr[2], bfr[2];

    // ---- phase 0: ks0 ----
    asm volatile("s_waitcnt vmcnt(0)" ::: "memory");
    asm volatile("s_barrier" ::: "memory");
    #pragma unroll
    for (int mt = 0; mt < 2; ++mt)
      afr[mt] = cat8(*(const i32x4*)(smem + bo + aOff + mt * 4096 + swk0_0),
                     *(const i32x4*)(smem + bo + aOff + mt * 4096 + swk0_1));
    #pragma unroll
    for (int nt = 0; nt < 2; ++nt)
      bfr[nt] = cat8(*(const i32x4*)(smem + bo + bOff + nt * 4096 + swk0_0),
                     *(const i32x4*)(smem + bo + bOff + nt * 4096 + swk0_1));
    YSTG_A(bn, kk);
    YSTG_BEV(bn, kk);
    __builtin_amdgcn_s_setprio(1);
    #pragma unroll
    for (int mt = 0; mt < 2; ++mt)
      #pragma unroll
      for (int nt = 0; nt < 2; ++nt)
        acc[mt][nt] = __builtin_amdgcn_mfma_scale_f32_32x32x64_f8f6f4(
            afr[mt], bfr[nt], acc[mt][nt], 0, 0, 0, 0x7F7F7F7F, 0, 0x7F7F7F7F);
    __builtin_amdgcn_s_setprio(0);

    // ---- phase 1: ks1 ----
    asm volatile("s_barrier" ::: "memory");
    #pragma unroll
    for (int mt = 0; mt < 2; ++mt)
      afr[mt] = cat8(*(const i32x4*)(smem + bo + aOff + mt * 4096 + swk1_0),
                     *(const i32x4*)(smem + bo + aOff + mt * 4096 + swk1_1));
    #pragma unroll
    for (int nt = 0; nt < 2; ++nt)
      bfr[nt] = cat8(*(const i32x4*)(smem + bo + bOff + nt * 4096 + swk1_0),
                     *(const i32x4*)(smem + bo + bOff + nt * 4096 + swk1_1));
    YSTG_BOD(bn, kk);
    __builtin_amdgcn_s_setprio(1);
    #pragma unroll
    for (int mt = 0; mt < 2; ++mt)
      #pragma unroll
      for (int nt = 0; nt < 2; ++nt)
        acc[mt][nt] = __builtin_amdgcn_mfma_scale_f32_32x32x64_f8f6f4(
            afr[mt], bfr[nt], acc[mt][nt], 0, 0, 0, 0x7F7F7F7F, 0, 0x7F7F7F7F);
    __builtin_amdgcn_s_setprio(0);
  }
#undef YSTG_A
#undef YSTG_BEV
#undef YSTG_BOD

  // C/D layout 32x32: col = lane&31, row = (r&3) + 8*(r>>2) + 4*(lane>>5)
  #pragma unroll
  for (int mt = 0; mt < 2; ++mt)
    #pragma unroll
    for (int nt = 0; nt < 2; ++nt) {
      const size_t colg = n0 + wn * 64 + nt * 32 + l31;
      #pragma unroll
      for (int r = 0; r < 16; ++r) {
        const size_t rowg = m0 + wm * 64 + mt * 32 + (r & 3) + 8 * (r >> 2) + 4 * hi;
        C8[rowg * ldc + colg] = f2e4m3(acc[mt][nt][r] * scale);
      }
    }
}

// ---------------- 256x256 fp8 GEMM (scores): mfma_scale 32x32x64, BK=128, 8 waves; fp8 output ----------------
__global__ __launch_bounds__(512, 2) void gemm8pF8(
    const unsigned char* __restrict__ A8, long long sA,
    const unsigned char* __restrict__ B8, long long sB,
    unsigned char* __restrict__ C8, int ldc, long long sC,
    float scale, int K) {
  __shared__ char smem[131072];
  const int tid = threadIdx.x;
  const int wave = tid >> 6, lane = tid & 63;
  const int wm = wave >> 2, wn = wave & 3;
  const int z = blockIdx.z;
  const size_t m0 = (size_t)blockIdx.y * 256;
  const size_t n0 = (size_t)blockIdx.x * 256;
  const unsigned char* Ab = A8 + (size_t)z * sA + m0 * K;
  const unsigned char* Bb = B8 + (size_t)z * sB + n0 * K;
  const int perL = (lane >> 3) * K + (((lane & 7) ^ (lane >> 3)) * 16);
  const int w4 = wave * 4;
  const int r7l = lane & 7;
  const int hi = lane >> 5;
  const int l31 = lane & 31;
  const int swk0_0 = ((hi * 2) ^ r7l) * 16;
  const int swk0_1 = ((hi * 2 + 1) ^ r7l) * 16;
  const int swk1_0 = ((4 + hi * 2) ^ r7l) * 16;
  const int swk1_1 = ((4 + hi * 2 + 1) ^ r7l) * 16;
  const int aOff = wm * 16384 + l31 * 128;
  const int bOff = 32768 + wn * 8192 + l31 * 128;

  f32x16 acc[4][2];
  #pragma unroll
  for (int i = 0; i < 4; ++i)
    #pragma unroll
    for (int j = 0; j < 2; ++j) acc[i][j] = (f32x16)(0.0f);

#define STG_A8(BUF, KK, C0) do { \
    glds16(Ab + (size_t)((w4 + (C0)) * 8) * K + perL + (KK), smem + (BUF) + (w4 + (C0)) * 1024); \
    glds16(Ab + (size_t)((w4 + (C0) + 1) * 8) * K + perL + (KK), smem + (BUF) + (w4 + (C0) + 1) * 1024); } while (0)
#define STG_B8(BUF, KK, C0) do { \
    glds16(Bb + (size_t)((w4 + (C0)) * 8) * K + perL + (KK), smem + (BUF) + 32768 + (w4 + (C0)) * 1024); \
    glds16(Bb + (size_t)((w4 + (C0) + 1) * 8) * K + perL + (KK), smem + (BUF) + 32768 + (w4 + (C0) + 1) * 1024); } while (0)

  const int NT = K >> 7;
  STG_A8(0, 0, 0); STG_A8(0, 0, 2); STG_B8(0, 0, 0); STG_B8(0, 0, 2);

  for (int t = 0; t < NT; ++t) {
    const int bo = (t & 1) * 65536;
    const int bn = bo ^ 65536;
    const int kk = (t + 1 < NT) ? (t + 1) * 128 : 0;
    i32x8 afr[4], bfr[2];

    // ---- phase 0: ks0, nt0 ----
    asm volatile("s_waitcnt vmcnt(0)" ::: "memory");
    asm volatile("s_barrier" ::: "memory");
    #pragma unroll
    for (int mt = 0; mt < 4; ++mt)
      afr[mt] = cat8(*(const i32x4*)(smem + bo + aOff + mt * 4096 + swk0_0),
                     *(const i32x4*)(smem + bo + aOff + mt * 4096 + swk0_1));
    bfr[0] = cat8(*(const i32x4*)(smem + bo + bOff + swk0_0),
                  *(const i32x4*)(smem + bo + bOff + swk0_1));
    STG_A8(bn, kk, 0); STG_B8(bn, kk, 0);
    __builtin_amdgcn_s_setprio(1);
    #pragma unroll
    for (int mt = 0; mt < 4; ++mt)
      acc[mt][0] = __builtin_amdgcn_mfma_scale_f32_32x32x64_f8f6f4(
          afr[mt], bfr[0], acc[mt][0], 0, 0, 0, 0x7F7F7F7F, 0, 0x7F7F7F7F);
    __builtin_amdgcn_s_setprio(0);

    // ---- phase 1: ks0, nt1 ----
    asm volatile("s_barrier" ::: "memory");
    bfr[1] = cat8(*(const i32x4*)(smem + bo + bOff + 4096 + swk0_0),
                  *(const i32x4*)(smem + bo + bOff + 4096 + swk0_1));
    STG_A8(bn, kk, 2); STG_B8(bn, kk, 2);
    __builtin_amdgcn_s_setprio(1);
    #pragma unroll
    for (int mt = 0; mt < 4; ++mt)
      acc[mt][1] = __builtin_amdgcn_mfma_scale_f32_32x32x64_f8f6f4(
          afr[mt], bfr[1], acc[mt][1], 0, 0, 0, 0x7F7F7F7F, 0, 0x7F7F7F7F);
    __builtin_amdgcn_s_setprio(0);

    // ---- phase 2: ks1, nt0 ----
    asm volatile("s_barrier" ::: "memory");
    #pragma unroll
    for (int mt = 0; mt < 4; ++mt)
      afr[mt] = cat8(*(const i32x4*)(smem + bo + aOff + mt * 4096 + swk1_0),
                     *(const i32x4*)(smem + bo + aOff + mt * 4096 + swk1_1));
    bfr[0] = cat8(*(const i32x4*)(smem + bo + bOff + swk1_0),
                  *(const i32x4*)(smem + bo + bOff + swk1_1));
    __builtin_amdgcn_s_setprio(1);
    #pragma unroll
    for (int mt = 0; mt < 4; ++mt)
      acc[mt][0] = __builtin_amdgcn_mfma_scale_f32_32x32x64_f8f6f4(
          afr[mt], bfr[0], acc[mt][0], 0, 0, 0, 0x7F7F7F7F, 0, 0x7F7F7F7F);
    __builtin_amdgcn_s_setprio(0);

    // ---- phase 3: ks1, nt1 ----
    asm volatile("s_barrier" ::: "memory");
    bfr[1] = cat8(*(const i32x4*)(smem + bo + bOff + 4096 + swk1_0),
                  *(const i32x4*)(smem + bo + bOff + 4096 + swk1_1));
    __builtin_amdgcn_s_setprio(1);
    #pragma unroll
    for (int mt = 0; mt < 4; ++mt)
      acc[mt][1] = __builtin_amdgcn_mfma_scale_f32_32x32x64_f8f6f4(
          afr[mt], bfr[1], acc[mt][1], 0, 0, 0, 0x7F7F7F7F, 0, 0x7F7F7F7F);
    __builtin_amdgcn_s_setprio(0);
  }
#undef STG_A8
#undef STG_B8

  // C/D layout 32x32: col = lane&31, row = (r&3) + 8*(r>>2) + 4*(lane>>5)
  unsigned char* Cz = C8 + (size_t)z * sC;
  #pragma unroll
  for (int mt = 0; mt < 4; ++mt)
    #pragma unroll
    for (int nt = 0; nt < 2; ++nt) {
      const size_t colg = n0 + wn * 64 + nt * 32 + l31;
      #pragma unroll
      for (int r = 0; r < 16; ++r) {
        const size_t rowg = m0 + wm * 128 + mt * 32 + (r & 3) + 8 * (r >> 2) + 4 * hi;
        Cz[rowg * ldc + colg] = f2e4m3(acc[mt][nt][r] * scale);
      }
    }
}

// ---------------- row softmax + prior transform; emits na row, ell, dvec (fp8 Sb input) ----------------
__global__ __launch_bounds__(256) void softmax_kernel(const unsigned char* __restrict__ Sb,
                                                      const float* __restrict__ bvec,
                                                      const float* __restrict__ prior,
                                                      float* __restrict__ na,
                                                      float* __restrict__ ell,
                                                      float* __restrict__ dvec) {
  const int row = blockIdx.x;
  const int t = threadIdx.x;
  const int b = row >> 11, i = row & (S_LEN - 1);
  const uint2 sv = ((const uint2*)(Sb + (size_t)row * S_LEN))[t];
  const f32x4 bv0 = ((const f32x4*)(bvec + (size_t)b * S_LEN))[t * 2];
  const f32x4 bv1 = ((const f32x4*)(bvec + (size_t)b * S_LEN))[t * 2 + 1];
  float v[8];
  #pragma unroll
  for (int u = 0; u < 8; ++u) {
    const unsigned word = (u < 4) ? sv.x : sv.y;
    const float sc = e4m32f((unsigned char)(word >> ((u & 3) * 8))) * 0.0625f;
    v[u] = sc + ((u < 4) ? bv0[u] : bv1[u - 4]);
  }
  float mx = v[0];
  #pragma unroll
  for (int u = 1; u < 8; ++u) mx = fmaxf(mx, v[u]);
  for (int o = 32; o > 0; o >>= 1) mx = fmaxf(mx, __shfl_xor(mx, o));
  __shared__ float red[4], red2[4];
  const int wave = t >> 6, lane = t & 63;
  if (lane == 0) red[wave] = mx;
  __syncthreads();
  mx = fmaxf(fmaxf(red[0], red[1]), fmaxf(red[2], red[3]));
  float e[8], s = 0.0f;
  #pragma unroll
  for (int u = 0; u < 8; ++u) { e[u] = __expf(v[u] - mx); s += e[u]; }
  for (int o = 32; o > 0; o >>= 1) s += __shfl_xor(s, o);
  if (lane == 0) red2[wave] = s;
  __syncthreads();
  s = red2[0] + red2[1] + red2[2] + red2[3];
  const float pr = prior[0];
  const float w = 1.0f - pr;
  const float inv = 1.0f / s;
  f32x4 o0, o1;
  #pragma unroll
  for (int u = 0; u < 4; ++u) o0[u] = pr + w * (e[u] * inv + 1e-9f);
  #pragma unroll
  for (int u = 0; u < 4; ++u) o1[u] = pr + w * (e[4 + u] * inv + 1e-9f);
  f32x4* nrow = (f32x4*)(na + (size_t)row * S_LEN);
  nrow[t * 2] = o0;
  nrow[t * 2 + 1] = o1;
  #pragma unroll
  for (int u = 0; u < 8; ++u) {
    const int j = t * 8 + u;
    const float ov = (u < 4) ? o0[u] : o1[u - 4];
    if (j == i) dvec[row] = ov;
    if (j == i + 1) ell[row] = logf(ov + 1e-9f);
  }
  if (i == S_LEN - 1 && t == 0) ell[row] = 0.0f;
}

// ---------------- exclusive prefix sum of ell -> Cpre ----------------
__global__ __launch_bounds__(256) void scan_kernel(const float* __restrict__ ell,
                                                   float* __restrict__ Cpre) {
  const int b = blockIdx.x, t = threadIdx.x;
  const float* eb = ell + (size_t)b * S_LEN;
  const f32x4 e0 = ((const f32x4*)eb)[t * 2];
  const f32x4 e1 = ((const f32x4*)eb)[t * 2 + 1];
  float ev[8];
  #pragma unroll
  for (int u = 0; u < 4; ++u) ev[u] = e0[u];
  #pragma unroll
  for (int u = 0; u < 4; ++u) ev[4 + u] = e1[u];
  float loc[8], tot = 0.0f;
  #pragma unroll
  for (int u = 0; u < 8; ++u) { loc[u] = tot; tot += ev[u]; }
  __shared__ float sbuf[256];
  sbuf[t] = tot;
  __syncthreads();
  for (int off = 1; off < 256; off <<= 1) {
    const float v = (t >= off) ? sbuf[t - off] : 0.0f;
    __syncthreads();
    sbuf[t] += v;
    __syncthreads();
  }
  const float base = (t == 0) ? 0.0f : sbuf[t - 1];
  #pragma unroll
  for (int u = 0; u < 8; ++u)
    Cpre[(size_t)b * S_LEN + t * 8 + u] = base + loc[u];
}

// ---------------- g_attn: exp(C[max]-C[min]) + 1e-9, diag from dvec ----------------
__global__ __launch_bounds__(256) void gattn_kernel(const float* __restrict__ Cpre,
                                                    const float* __restrict__ dvec,
                                                    float* __restrict__ g) {
  const int b = blockIdx.z, i = blockIdx.y;
  const int j0 = blockIdx.x * 1024 + threadIdx.x * 4;
  const float Ci = Cpre[b * S_LEN + i];
  const float di = dvec[b * S_LEN + i];
  const f32x4 Cj = *(const f32x4*)&Cpre[b * S_LEN + j0];
  f32x4 o;
  #pragma unroll
  for (int u = 0; u < 4; ++u) {
    const int j = j0 + u;
    const float arg = (j > i) ? (Cj[u] - Ci) : (Ci - Cj[u]);
    o[u] = (j == i) ? (di + 1e-9f) : (__expf(arg) + 1e-9f);
  }
  *(f32x4*)(g + ((size_t)b * S_LEN + i) * S_LEN + j0) = o;
}

extern "C" void kernel_launch(void* const* d_in, const int* in_sizes, int n_in,
                              void* d_out, int out_size, void* d_ws, size_t ws_size,
                              hipStream_t stream) {
  const float* ctx   = (const float*)d_in[0];
  // d_in[1] = eos_mask: numerically a no-op (mask * 1e-19 in fp32), never read.
  const float* prior = (const float*)d_in[2];
  const float* gamma = (const float*)d_in[3];
  const float* beta  = (const float*)d_in[4];
  const float* Wk    = (const float*)d_in[5];
  const float* Wq    = (const float*)d_in[7];
  const float* bq    = (const float*)d_in[8];

  float* g  = (float*)d_out;                               // g_attn output (also fp8 scores scratch)
  float* na = g + (size_t)NB * S_LEN * S_LEN;              // neibor_attn output

  // scratch inside the na output region (all dead before softmax overwrites it):
  unsigned char* X8 = (unsigned char*)na;                          // fp8 [8192][1024], 8 MiB
  unsigned char* Y8 = X8 + (size_t)(NB * S_LEN) * D_MODEL;         // fp8 [8192][1024], 8 MiB
  unsigned char* PT8 = Y8 + (size_t)(NB * S_LEN) * D_MODEL;        // fp8 [1024][1024], 1 MiB
  u16* Wt = (u16*)(PT8 + (size_t)D_MODEL * D_MODEL);               // [2048][1024] bf16, 4 MiB
  // fp8 scores live in the g output region (overwritten by gattn at the end):
  unsigned char* Sb = (unsigned char*)g;                           // [8192][2048] fp8, 16 MiB
  // small scratch in ws:
  float* w2   = (float*)d_ws;                                      // [1024]
  float* bvec = w2 + D_MODEL;                                      // [8192]
  float* ell  = bvec + NB * S_LEN;                                 // [8192]
  float* dvec = ell + NB * S_LEN;                                  // [8192]
  float* Cpre = dvec + NB * S_LEN;                                 // [8192]

  prep_w<<<dim3(32, 65), dim3(32, 8), 0, stream>>>(Wq, Wk, bq, Wt, w2);
  ln_kernel<<<NB * S_LEN, 256, 0, stream>>>(ctx, gamma, beta, w2, X8, bvec);

  // PT8[n][k] = fp8(16 * P[k][n]), P = Wq·Wk^T
  gemm_bt<<<dim3(8, 8, 1), 256, 0, stream>>>(Wt + (size_t)D_MODEL * D_MODEL, D_MODEL,
                                             Wt, D_MODEL,
                                             PT8, D_MODEL, 16.0f, D_MODEL);
  // Y8 = fp8(x·P)  (fp8 MFMA; 1/16 undoes PT pre-scale)
  gemm8pF8y<<<dim3(4, 64, 1), 512, 0, stream>>>(X8, PT8,
                                                Y8, D_MODEL, 1.0f / 16.0f, D_MODEL);
  // Sb[b] = fp8(16 * (y8[b] · x8[b]^T) / d)  (fp8 MFMA, fp8 out; softmax decodes with 1/16)
  gemm8pF8<<<dim3(8, 8, NB), 512, 0, stream>>>(Y8, (long long)S_LEN * D_MODEL,
                                               X8, (long long)S_LEN * D_MODEL,
                                               Sb, S_LEN, (long long)S_LEN * S_LEN,
                                               16.0f / (float)D_MODEL, D_MODEL);

  softmax_kernel<<<NB * S_LEN, 256, 0, stream>>>(Sb, bvec, prior, na, ell, dvec);
  scan_kernel<<<NB, 256, 0, stream>>>(ell, Cpre);
  gattn_kernel<<<dim3(2, S_LEN, NB), 256, 0, stream>>>(Cpre, dvec, g);
}